// Round 3
// baseline (180.834 us; speedup 1.0000x reference)
//
#include <hip/hip_runtime.h>

#define CMIN -1024.0f
#define CMAX 1016.0f

__device__ __forceinline__ float clampv(float x) {
    return fminf(fmaxf(x, CMIN), CMAX);
}

__device__ __forceinline__ float wave_reduce(float v) {
    #pragma unroll
    for (int off = 32; off > 0; off >>= 1)
        v += __shfl_down(v, off, 64);
    return v;
}

// ws layout: ws[0..8191] = per-c-block DC partial sums (ch0: 0..4095,
//            ch1: 4096..8191); ws[8192..139263] = compact pre-adjust DC values.

// ---------------------------------------------------------------------------
// Kernel 1: full payload (y then c), one float4/thread, one-shot grid.
//   y blocks (0..16383):   out = clamp(clamp(y)*1.9)
//   c blocks (16384..24575): out = clamp(clamp(c)*1.9), except DC slots get a
//     placeholder; DC threads also (a) add clamp(c_dc) into a per-block
//     partial -> ws[b_c], (b) store the pre-clamp value clamp(c)*1.9 into the
//     compact dcbuf for kernel 2's fixup. No scattered gather -> no 17 MB
//     line overfetch. ynvec % 256 == 0, so the y/c branch is block-uniform.
// ---------------------------------------------------------------------------
__global__ void __launch_bounds__(256)
payload_kernel(const float4* __restrict__ y4, const float4* __restrict__ c4,
               float4* __restrict__ out, float* __restrict__ partials,
               float* __restrict__ dcbuf, int ynvec, int yblocks)
{
    const int tid = blockIdx.x * blockDim.x + threadIdx.x;

    if (tid < ynvec) {
        float4 v = y4[tid];
        v.x = clampv(clampv(v.x) * 1.9f);
        v.y = clampv(clampv(v.y) * 1.9f);
        v.z = clampv(clampv(v.z) * 1.9f);
        v.w = clampv(clampv(v.w) * 1.9f);
        out[tid] = v;
    } else {
        const int ic = tid - ynvec;
        float4 v = c4[ic];
        float4 r;
        r.x = clampv(v.x) * 1.9f;
        r.y = clampv(v.y) * 1.9f;
        r.z = clampv(v.z) * 1.9f;
        r.w = clampv(v.w) * 1.9f;

        float dcv = 0.0f;
        if ((ic & 15) == 0) {             // DC element of its 8x8 block
            dcv = clampv(v.x);            // clamped DC for the mean
            dcbuf[ic >> 4] = r.x;         // pre-adjust, pre-final-clamp value
        }
        r.x = clampv(r.x);                // placeholder for DC slots (fixed by K2)
        r.y = clampv(r.y);
        r.z = clampv(r.z);
        r.w = clampv(r.w);
        out[tid] = r;

        // per-block DC partial (16 nonzero lanes per block)
        __shared__ float smem[4];
        float s = wave_reduce(dcv);
        const int lane = threadIdx.x & 63;
        const int wave = threadIdx.x >> 6;
        if (lane == 0) smem[wave] = s;
        __syncthreads();
        if (threadIdx.x == 0)
            partials[blockIdx.x - yblocks] = smem[0] + smem[1] + smem[2] + smem[3];
    }
}

// ---------------------------------------------------------------------------
// Kernel 2: DC fixup. 512 blocks x 256 threads = 131072 threads, one DC each.
//   Prologue: each block reduces the 8192 partials (32 KB, L2/L3-resident) to
//   both channel adjustments; the compact dcbuf load is issued first so its
//   latency hides under the reduce. Then one scattered 4 B store per thread.
// ---------------------------------------------------------------------------
__global__ void __launch_bounds__(256)
dc_fixup(float* __restrict__ outf, const float* __restrict__ partials,
         const float* __restrict__ dcbuf, int dc_per_ch,
         float neg09_inv_count)
{
    const int d = blockIdx.x * blockDim.x + threadIdx.x;

    // issue compact payload load first
    const float pre = dcbuf[d];

    // prologue: both channel sums from 8192 partials
    float s0 = 0.0f, s1 = 0.0f;
    for (int j = threadIdx.x; j < 4096; j += 256) {
        s0 += partials[j];
        s1 += partials[4096 + j];
    }
    s0 = wave_reduce(s0);
    s1 = wave_reduce(s1);

    __shared__ float sm[8];
    __shared__ float sadj[2];
    const int lane = threadIdx.x & 63;
    const int wave = threadIdx.x >> 6;
    if (lane == 0) { sm[wave] = s0; sm[4 + wave] = s1; }
    __syncthreads();
    if (threadIdx.x == 0) {
        sadj[0] = (sm[0] + sm[1] + sm[2] + sm[3]) * neg09_inv_count;
        sadj[1] = (sm[4] + sm[5] + sm[6] + sm[7]) * neg09_inv_count;
    }
    __syncthreads();

    const float adj = (d < dc_per_ch) ? sadj[0] : sadj[1];
    outf[(size_t)d * 64] = clampv(pre + adj);
}

extern "C" void kernel_launch(void* const* d_in, const int* in_sizes, int n_in,
                              void* d_out, int out_size, void* d_ws, size_t ws_size,
                              hipStream_t stream) {
    const float* y = (const float*)d_in[0];
    const float* c = (const float*)d_in[1];
    float* out = (float*)d_out;
    float* ws  = (float*)d_ws;

    const int yN = in_sizes[0];             // 16777216 floats
    const int cN = in_sizes[1];             // 8388608 floats

    const int ynvec    = yN / 4;            // 4194304 float4
    const int cnvec    = cN / 4;            // 2097152 float4
    const int yblocks  = ynvec / 256;       // 16384
    const int cblocks  = cnvec / 256;       // 8192
    const int dc_count = cN / 64;           // 131072
    const int dc_per_ch = dc_count / 2;     // 65536
    const float neg09_inv_count = -0.9f / (float)dc_per_ch;

    float* partials = ws;                   // 8192 floats
    float* dcbuf    = ws + 8192;            // 131072 floats

    // Kernel 1: full payload + DC partials + compact DC stash
    payload_kernel<<<yblocks + cblocks, 256, 0, stream>>>(
        (const float4*)y, (const float4*)c, (float4*)out, partials, dcbuf,
        ynvec, yblocks);

    // Kernel 2: micro fixup of the 131072 DC outputs
    dc_fixup<<<dc_count / 256, 256, 0, stream>>>(
        out + (size_t)yN, partials, dcbuf, dc_per_ch, neg09_inv_count);
}